// Round 2
// 139.505 us; speedup vs baseline: 1.0386x; 1.0386x over previous
//
#include <hip/hip_runtime.h>

// AttentionLayer: B=2,T=12,N=1024,D=128,H=8,HD=16
// R13 = R12 (32x32x16-MFMA attention rebuild) with pack_bf16 reverted to the
// R11-verified round-half-up perm trick. R12's inline-asm v_cvt_pk_bf16_f32
// failed absmax 5.6e-4 (vs 1.3e-4): consistent with truncating conversion;
// systematic -0.5ulp bias on V/P/O doesn't cancel. Layout was correct.
//  - QK^T: one mfma_f32_32x32x16_bf16 per 32j x 32q window (wave owns 32 q rows,
//    block owns 128 -> grid (8,8,24), K/V LDS re-read traffic halves vs R11).
//  - PV: C=[hd][q] via mfma(A=V, B=P); V has bf16-ones rows at m=16 and m=20 so
//    acc[8] is the softmax denominator in-lane for BOTH lane halves (free).
//  - K LDS: per-window 64 linear 16B blocks; j-row permutation pi (swap bits 2,3)
//    folded into the staging write so S^T C-regs ARE PV's B-frag after exp+pack.
//    Lane l reads block l -> zero-conflict ds_read_b128.
//  - V LDS: 272-B row stride (odd multiple of 16B) -> balanced conflict-free
//    b128 reads, pure immediate offsets.
// qkv_proj / o_proj unchanged. XCD swizzle kept (grid.x = head).

#define DEV __device__ __forceinline__

typedef __attribute__((ext_vector_type(4))) float f32x4;
typedef __attribute__((ext_vector_type(16))) float f32x16;
typedef __attribute__((ext_vector_type(8))) short s16x8;
typedef __attribute__((ext_vector_type(4))) short s16x4;
typedef __attribute__((ext_vector_type(2))) unsigned int u32x2;
typedef __attribute__((ext_vector_type(4))) unsigned int u32x4;

DEV unsigned short f2bf(float f) {          // fp32 -> bf16, round-nearest-even
    unsigned u = __builtin_bit_cast(unsigned, f);
    u = (u + 0x7fffu + ((u >> 16) & 1u)) >> 16;
    return (unsigned short)u;
}

DEV unsigned pack_bf16(float a, float b) {  // {lo=bf16(a), hi=bf16(b)}
    // round-half-up: 3 VALU ops; bias cancels in softmax ratio (R4-R11: absmax ok)
    unsigned ua = __builtin_bit_cast(unsigned, a) + 0x8000u;
    unsigned ub = __builtin_bit_cast(unsigned, b) + 0x8000u;
    return __builtin_amdgcn_perm(ub, ua, 0x07060302);  // {ub.hi16, ua.hi16}
}

DEV f32x16 mfma3216(s16x8 a, s16x8 b, f32x16 c) {
    return __builtin_amdgcn_mfma_f32_32x32x16_bf16(a, b, c, 0, 0, 0);
}

// ---------------------------------------------------------------- qkv proj ---
// grid (384, 3): x = 64-row tile of M=24576, y = which of q/k/v.
__global__ __launch_bounds__(256)
void qkv_proj_kernel(const float* __restrict__ xq, const float* __restrict__ xk,
                     const float* __restrict__ xv,
                     const float* __restrict__ Wq, const float* __restrict__ Wk,
                     const float* __restrict__ Wv,
                     const float* __restrict__ bq, const float* __restrict__ bk,
                     const float* __restrict__ bv,
                     unsigned short* __restrict__ oq, unsigned short* __restrict__ ok,
                     unsigned short* __restrict__ ov)
{
    const int z = blockIdx.y;
    const float* X    = (z == 0) ? xq : (z == 1) ? xk : xv;
    const float* W    = (z == 0) ? Wq : (z == 1) ? Wk : Wv;
    const float* bias = (z == 0) ? bq : (z == 1) ? bk : bv;
    unsigned short* out = (z == 0) ? oq : (z == 1) ? ok : ov;
    const float scale = (z == 0) ? 0.25f * 1.44269504088896f : 1.0f;

    __shared__ unsigned short Xs[64 * 136];
    __shared__ unsigned short Ws[128 * 136];

    const int t  = threadIdx.x;
    const int m0 = blockIdx.x * 64;

    {
        const float4* Xg = (const float4*)(X + (size_t)m0 * 128);
        #pragma unroll
        for (int p = 0; p < 8; p++) {
            int g = p * 256 + t;
            float4 vv = Xg[g];
            int row = g >> 5, c4 = g & 31;
            ushort4 d;
            d.x = f2bf(vv.x); d.y = f2bf(vv.y); d.z = f2bf(vv.z); d.w = f2bf(vv.w);
            *(ushort4*)&Xs[row * 136 + c4 * 4] = d;
        }
        const float4* Wg = (const float4*)W;
        #pragma unroll
        for (int p = 0; p < 16; p++) {
            int g = p * 256 + t;
            float4 vv = Wg[g];
            int row = g >> 5, c4 = g & 31;
            ushort4 d;
            d.x = f2bf(vv.x); d.y = f2bf(vv.y); d.z = f2bf(vv.z); d.w = f2bf(vv.w);
            *(ushort4*)&Ws[row * 136 + c4 * 4] = d;
        }
    }
    __syncthreads();

    const int wave = t >> 6, lane = t & 63, quad = lane >> 4, n16 = lane & 15;
    f32x4 acc[8];
    const f32x4 zero4 = {0.f, 0.f, 0.f, 0.f};
    #pragma unroll
    for (int i = 0; i < 8; i++) acc[i] = zero4;

    #pragma unroll
    for (int ks = 0; ks < 4; ks++) {
        s16x8 a = *(const s16x8*)&Xs[(wave * 16 + n16) * 136 + ks * 32 + quad * 8];
        #pragma unroll
        for (int nt = 0; nt < 8; nt++) {
            s16x8 b = *(const s16x8*)&Ws[(nt * 16 + n16) * 136 + ks * 32 + quad * 8];
            acc[nt] = __builtin_amdgcn_mfma_f32_16x16x32_bf16(a, b, acc[nt], 0, 0, 0);
        }
    }

    const int bt    = m0 >> 10;
    const int nbase = (m0 & 1023) + wave * 16 + quad * 4;
    if (z == 2) {
        // V transposed [bt][h][hd][n]: lane holds 4 consecutive n for hd=n16
        #pragma unroll
        for (int nt = 0; nt < 8; nt++) {
            float bb = bias[nt * 16 + n16];
            u32x2 pv = {pack_bf16(acc[nt][0] + bb, acc[nt][1] + bb),
                        pack_bf16(acc[nt][2] + bb, acc[nt][3] + bb)};
            *(u32x2*)&out[((size_t)(bt * 8 + nt) * 16 + n16) * 1024 + nbase] = pv;
        }
    } else {
        // q/k [bt][h][n][hd]: transpose through Xs (done with it) -> coalesced stores
        __syncthreads();
        const int crow = wave * 16 + quad * 4;
        #pragma unroll
        for (int nt = 0; nt < 8; nt++) {
            float bb = bias[nt * 16 + n16];
            #pragma unroll
            for (int r = 0; r < 4; r++)
                Xs[(crow + r) * 136 + nt * 16 + n16] = f2bf((acc[nt][r] + bb) * scale);
        }
        __syncthreads();
        #pragma unroll
        for (int p = 0; p < 4; p++) {
            int g = p * 256 + t, row = g >> 4, ch = g & 15;   // ch*8 = h*16 + seg
            s16x8 val = *(const s16x8*)&Xs[row * 136 + ch * 8];
            *(s16x8*)&out[((size_t)(bt * 8 + (ch >> 1)) * 1024 + (m0 & 1023) + row) * 16
                          + (ch & 1) * 8] = val;
        }
    }
}

// ---------------------------------------------------------------- attention ---
// grid (8, 8, 24): x = head (XCD swizzle: flat%8 == h), y = 128-row q block,
// z = bt.  4 waves x 32 q-rows each.  128-j chunks, double-buffered.
// LDS: K 2x4KB linear-block window tiles @0, V 2x(21 rows x 272B) @8192.
__global__ __launch_bounds__(256, 6)
void attn_kernel(const unsigned short* __restrict__ q,
                 const unsigned short* __restrict__ k,
                 const unsigned short* __restrict__ vt,
                 unsigned short* __restrict__ O)
{
    __shared__ unsigned char smem[8192 + 2 * 5712];   // 19616 B

    const int t    = threadIdx.x;
    const int lane = t & 63;
    const int wave = t >> 6;
    const int hi   = lane >> 5;          // lane half
    const int l31  = lane & 31;
    const int h = blockIdx.x, bx = blockIdx.y, bt = blockIdx.z;
    const size_t headoff = (size_t)(bt * 8 + h) * 16384;

    const int q0 = bx * 128 + wave * 32;

    // Q B-frag (loop-invariant): B[k=hd][n=q]; lane: n=q0+l31, hd=hi*8..+7
    s16x8 qf = *(const s16x8*)(q + headoff + (size_t)(q0 + l31) * 16 + hi * 8);

    // --- staging (whole block, 1 K b128 + 1 V b128 per thread per chunk) ---
    // K: thread -> chunk row = t>>1, hd-half s = t&1.
    //    dest block: window w=row>>5, m = pi(row&31)  (pi: swap bits 2,3)
    const int krow = t >> 1, kss = t & 1;
    const int kj   = krow & 31;
    const int km   = (kj & ~12) | ((kj & 4) << 1) | ((kj & 8) >> 1);
    const unsigned kdst = (unsigned)((krow >> 5) * 1024 + kss * 512 + km * 16);
    const unsigned short* kg = k + headoff + (size_t)krow * 16 + kss * 8;
    // V: thread -> hd row = t>>4, j-octet = t&15 ; dest row*272 + jblk*16
    const int vrow = t >> 4, vjb = t & 15;
    const unsigned vdst = (unsigned)(8192 + vrow * 272 + vjb * 16);
    const unsigned short* vg = vt + headoff + (size_t)vrow * 1024 + vjb * 8;

    // --- read bases ---
    const unsigned krd = (unsigned)(lane * 16);              // + buf*4096 + w*1024
    const int vr = (l31 > 20) ? 20 : l31;                    // rows >20 -> ones row
    const unsigned vrd = (unsigned)(8192 + vr * 272 + hi * 16);  // + buf*5712 + imm

    // --- constant V rows: ones at 16 & 20 (denominator), zeros 17..19; both bufs
    for (int idx = t; idx < 640; idx += 256) {
        int b = idx / 320, rem = idx - b * 320;
        int row = 16 + (rem >> 6), col = rem & 63;
        unsigned val = (row == 16 || row == 20) ? 0x3F803F80u : 0u;
        *(unsigned*)&smem[8192 + b * 5712 + row * 272 + col * 4] = val;
    }

    // --- prologue: stage chunk 0 into buffer 0 ---
    {
        s16x8 kv = *(const s16x8*)kg;
        s16x8 vv = *(const s16x8*)vg;
        *(s16x8*)&smem[kdst] = kv;
        *(s16x8*)&smem[vdst] = vv;
    }

    f32x16 acc;
    #pragma unroll
    for (int i = 0; i < 16; i++) acc[i] = 0.f;
    f32x16 zero16;
    #pragma unroll
    for (int i = 0; i < 16; i++) zero16[i] = 0.f;

    #pragma unroll
    for (int c = 0; c < 8; c++) {
        __syncthreads();                          // buf[c&1] ready; other free
        s16x8 kv, vv;
        if (c < 7) {                              // issue next chunk's loads now
            kv = *(const s16x8*)(kg + (size_t)(c + 1) * 2048);
            vv = *(const s16x8*)(vg + (size_t)(c + 1) * 128);
        }
        const unsigned kb = krd + (c & 1) * 4096;
        const unsigned vb = vrd + (c & 1) * 5712;
        #pragma unroll
        for (int w = 0; w < 4; w++) {             // 4 windows of 32 j
            // S^T = K*Q for 32j x 32q in ONE mfma: C[m][q], j = pi(m) folded in
            s16x8 ka = *(const s16x8*)&smem[kb + w * 1024];
            f32x16 s = mfma3216(ka, qf, zero16);
            float p[16];
            #pragma unroll
            for (int i = 0; i < 16; i++) p[i] = __builtin_amdgcn_exp2f(s[i]);
            // regs 0..7 -> P[j0..j0+15] B-frag, regs 8..15 -> P[j0+16..j0+31]
            u32x4 pa0 = {pack_bf16(p[0],  p[1]),  pack_bf16(p[2],  p[3]),
                         pack_bf16(p[4],  p[5]),  pack_bf16(p[6],  p[7])};
            u32x4 pa1 = {pack_bf16(p[8],  p[9]),  pack_bf16(p[10], p[11]),
                         pack_bf16(p[12], p[13]), pack_bf16(p[14], p[15])};
            // PV: C[hd][q] = V * P ; rows 16/20 of V are ones -> acc[8] = denom
            s16x8 vf0 = *(const s16x8*)&smem[vb + w * 64];
            s16x8 vf1 = *(const s16x8*)&smem[vb + w * 64 + 32];
            acc = mfma3216(vf0, __builtin_bit_cast(s16x8, pa0), acc);
            acc = mfma3216(vf1, __builtin_bit_cast(s16x8, pa1), acc);
        }
        if (c < 7) {                              // land prefetched chunk
            *(s16x8*)&smem[kdst + (((c + 1) & 1) ? 4096u : 0u)] = kv;
            *(s16x8*)&smem[vdst + (((c + 1) & 1) ? 5712u : 0u)] = vv;
        }
    }

    // --- epilogue: acc[8] = denominator (C row 16 lo / 20 hi, both ones rows) ---
    float dinv = __builtin_amdgcn_rcpf(acc[8]);
    __syncthreads();                              // all K/V reads retired
    // Otile [128 q][20 shorts pad] reusing K region; lane owns q-col = l31,
    // hd rows: lo {0-3,8-11}, hi {4-7,12-15}
    const unsigned ob = (unsigned)((wave * 32 + l31) * 40);
    u32x2 w0 = { pack_bf16(acc[0] * dinv, acc[1] * dinv),
                 pack_bf16(acc[2] * dinv, acc[3] * dinv) };
    u32x2 w1 = { pack_bf16(acc[4] * dinv, acc[5] * dinv),
                 pack_bf16(acc[6] * dinv, acc[7] * dinv) };
    *(u32x2*)&smem[ob + hi * 8]      = w0;        // hd 0-3 / 4-7
    *(u32x2*)&smem[ob + 16 + hi * 8] = w1;        // hd 8-11 / 12-15
    __syncthreads();
    {
        int qq = t >> 1, half = t & 1;
        s16x8 ov = *(const s16x8*)&smem[qq * 40 + half * 16];
        *(s16x8*)&O[((size_t)bt * 1024 + bx * 128 + qq) * 128 + h * 16 + half * 8] = ov;
    }
}

// ---------------------------------------------------------------- out proj ---
// X is bf16 (attn output) -> straight b128 staging; W fp32 -> bf16 in LDS.
__global__ __launch_bounds__(256)
void o_proj_kernel(const unsigned short* __restrict__ X, const float* __restrict__ W,
                   const float* __restrict__ bias, float* __restrict__ out)
{
    __shared__ unsigned short Xs[64 * 136];
    __shared__ unsigned short Ws[128 * 136];

    const int t  = threadIdx.x;
    const int m0 = blockIdx.x * 64;

    {
        #pragma unroll
        for (int p = 0; p < 4; p++) {          // 64x128 bf16: 1024 b128 chunks
            int g = p * 256 + t, row = g >> 4, ch = g & 15;
            *(s16x8*)&Xs[row * 136 + ch * 8] =
                *(const s16x8*)(X + (size_t)(m0 + row) * 128 + ch * 8);
        }
        const float4* Wg = (const float4*)W;
        #pragma unroll
        for (int p = 0; p < 16; p++) {
            int g = p * 256 + t;
            float4 vv = Wg[g];
            int row = g >> 5, c4 = g & 31;
            ushort4 d;
            d.x = f2bf(vv.x); d.y = f2bf(vv.y); d.z = f2bf(vv.z); d.w = f2bf(vv.w);
            *(ushort4*)&Ws[row * 136 + c4 * 4] = d;
        }
    }
    __syncthreads();

    const int wave = t >> 6, lane = t & 63, quad = lane >> 4, n16 = lane & 15;
    f32x4 acc[8];
    const f32x4 zero4 = {0.f, 0.f, 0.f, 0.f};
    #pragma unroll
    for (int i = 0; i < 8; i++) acc[i] = zero4;

    #pragma unroll
    for (int ks = 0; ks < 4; ks++) {
        s16x8 a = *(const s16x8*)&Xs[(wave * 16 + n16) * 136 + ks * 32 + quad * 8];
        #pragma unroll
        for (int nt = 0; nt < 8; nt++) {
            s16x8 b = *(const s16x8*)&Ws[(nt * 16 + n16) * 136 + ks * 32 + quad * 8];
            acc[nt] = __builtin_amdgcn_mfma_f32_16x16x32_bf16(a, b, acc[nt], 0, 0, 0);
        }
    }

    const int mrow = m0 + wave * 16 + quad * 4;
    #pragma unroll
    for (int nt = 0; nt < 8; nt++) {
        float bb = bias[nt * 16 + n16];
        #pragma unroll
        for (int r = 0; r < 4; r++)
            out[(size_t)(mrow + r) * 128 + nt * 16 + n16] = acc[nt][r] + bb;
    }
}

// ------------------------------------------------------------------ launch ---
extern "C" void kernel_launch(void* const* d_in, const int* in_sizes, int n_in,
                              void* d_out, int out_size, void* d_ws, size_t ws_size,
                              hipStream_t stream)
{
    const float* query = (const float*)d_in[0];
    const float* key_  = (const float*)d_in[1];
    const float* value = (const float*)d_in[2];
    const float* Wq = (const float*)d_in[3];
    const float* bq = (const float*)d_in[4];
    const float* Wk = (const float*)d_in[5];
    const float* bk = (const float*)d_in[6];
    const float* Wv = (const float*)d_in[7];
    const float* bv = (const float*)d_in[8];
    const float* Wo = (const float*)d_in[9];
    const float* bo = (const float*)d_in[10];
    float* out = (float*)d_out;

    char* ws = (char*)d_ws;
    unsigned short* qb = (unsigned short*)(ws);             // [bt][h][n][hd] bf16
    unsigned short* kb = (unsigned short*)(ws + 6291456);   // [bt][h][n][hd] bf16
    unsigned short* vb = (unsigned short*)(ws + 12582912);  // [bt][h][hd][n] bf16
    unsigned short* Ob = (unsigned short*)(ws + 18874368);  // [bt*1024][128] bf16

    qkv_proj_kernel<<<dim3(384, 3, 1), 256, 0, stream>>>(
        query, key_, value, Wq, Wk, Wv, bq, bk, bv, qb, kb, vb);
    attn_kernel<<<dim3(8, 8, 24), 256, 0, stream>>>(qb, kb, vb, Ob);
    o_proj_kernel<<<dim3(384, 1, 1), 256, 0, stream>>>(Ob, Wo, bo, out);
}

// Round 3
// 137.759 us; speedup vs baseline: 1.0518x; 1.0127x over previous
//
#include <hip/hip_runtime.h>

// AttentionLayer: B=2,T=12,N=1024,D=128,H=8,HD=16
// R14 = R13 attn with staging rebuilt on global_load_lds (width 16) +
// pre-swizzled global sources:
//  - K: j-permutation pi (swap bits 2,3) folded into per-lane GLOBAL address;
//    LDS dest is linear base+lane*16 (wave-uniform). No staging VGPRs/ds_writes.
//  - V: XOR-swizzled layout block(m,o) @ m*256 + (o^(m&7))*16, swizzle folded
//    into staging thread's global octet; reads hit all 8 bank-slots evenly.
//    vf1 = vf0 ^ 32 (XOR identity). V chunk 4 KB (was 5712 B + const rows).
//  - Denominator: A-lanes 16..31 read a broadcast 16B ones block -> C rows
//    16..31 are column sums; acc[8] (= C row 16/20) is the denom. Free.
//  - VGPRs ~65 -> fits launch_bounds(256,6) without spills (R13 likely spilled:
//    acc16+zero16+s16+p16+staging16 > 85-reg budget at 6 waves/SIMD).
// qkv_proj / o_proj unchanged (R13-verified). pack_bf16 = round-half-up perm
// trick (R12's v_cvt_pk_bf16_f32 truncates -> absmax fail; do not revert).

#define DEV __device__ __forceinline__

typedef __attribute__((ext_vector_type(4))) float f32x4;
typedef __attribute__((ext_vector_type(16))) float f32x16;
typedef __attribute__((ext_vector_type(8))) short s16x8;
typedef __attribute__((ext_vector_type(4))) short s16x4;
typedef __attribute__((ext_vector_type(2))) unsigned int u32x2;
typedef __attribute__((ext_vector_type(4))) unsigned int u32x4;

DEV unsigned short f2bf(float f) {          // fp32 -> bf16, round-nearest-even
    unsigned u = __builtin_bit_cast(unsigned, f);
    u = (u + 0x7fffu + ((u >> 16) & 1u)) >> 16;
    return (unsigned short)u;
}

DEV unsigned pack_bf16(float a, float b) {  // {lo=bf16(a), hi=bf16(b)}
    // round-half-up: 3 VALU ops; bias cancels in softmax ratio (R4-R13: absmax ok)
    unsigned ua = __builtin_bit_cast(unsigned, a) + 0x8000u;
    unsigned ub = __builtin_bit_cast(unsigned, b) + 0x8000u;
    return __builtin_amdgcn_perm(ub, ua, 0x07060302);  // {ub.hi16, ua.hi16}
}

DEV f32x16 mfma3216(s16x8 a, s16x8 b, f32x16 c) {
    return __builtin_amdgcn_mfma_f32_32x32x16_bf16(a, b, c, 0, 0, 0);
}

DEV void gload16(const unsigned short* g, unsigned short* l) {
    __builtin_amdgcn_global_load_lds(
        (const __attribute__((address_space(1))) unsigned int*)g,
        (__attribute__((address_space(3))) unsigned int*)l, 16, 0, 0);
}

// ---------------------------------------------------------------- qkv proj ---
// grid (384, 3): x = 64-row tile of M=24576, y = which of q/k/v.
__global__ __launch_bounds__(256)
void qkv_proj_kernel(const float* __restrict__ xq, const float* __restrict__ xk,
                     const float* __restrict__ xv,
                     const float* __restrict__ Wq, const float* __restrict__ Wk,
                     const float* __restrict__ Wv,
                     const float* __restrict__ bq, const float* __restrict__ bk,
                     const float* __restrict__ bv,
                     unsigned short* __restrict__ oq, unsigned short* __restrict__ ok,
                     unsigned short* __restrict__ ov)
{
    const int z = blockIdx.y;
    const float* X    = (z == 0) ? xq : (z == 1) ? xk : xv;
    const float* W    = (z == 0) ? Wq : (z == 1) ? Wk : Wv;
    const float* bias = (z == 0) ? bq : (z == 1) ? bk : bv;
    unsigned short* out = (z == 0) ? oq : (z == 1) ? ok : ov;
    const float scale = (z == 0) ? 0.25f * 1.44269504088896f : 1.0f;

    __shared__ unsigned short Xs[64 * 136];
    __shared__ unsigned short Ws[128 * 136];

    const int t  = threadIdx.x;
    const int m0 = blockIdx.x * 64;

    {
        const float4* Xg = (const float4*)(X + (size_t)m0 * 128);
        #pragma unroll
        for (int p = 0; p < 8; p++) {
            int g = p * 256 + t;
            float4 vv = Xg[g];
            int row = g >> 5, c4 = g & 31;
            ushort4 d;
            d.x = f2bf(vv.x); d.y = f2bf(vv.y); d.z = f2bf(vv.z); d.w = f2bf(vv.w);
            *(ushort4*)&Xs[row * 136 + c4 * 4] = d;
        }
        const float4* Wg = (const float4*)W;
        #pragma unroll
        for (int p = 0; p < 16; p++) {
            int g = p * 256 + t;
            float4 vv = Wg[g];
            int row = g >> 5, c4 = g & 31;
            ushort4 d;
            d.x = f2bf(vv.x); d.y = f2bf(vv.y); d.z = f2bf(vv.z); d.w = f2bf(vv.w);
            *(ushort4*)&Ws[row * 136 + c4 * 4] = d;
        }
    }
    __syncthreads();

    const int wave = t >> 6, lane = t & 63, quad = lane >> 4, n16 = lane & 15;
    f32x4 acc[8];
    const f32x4 zero4 = {0.f, 0.f, 0.f, 0.f};
    #pragma unroll
    for (int i = 0; i < 8; i++) acc[i] = zero4;

    #pragma unroll
    for (int ks = 0; ks < 4; ks++) {
        s16x8 a = *(const s16x8*)&Xs[(wave * 16 + n16) * 136 + ks * 32 + quad * 8];
        #pragma unroll
        for (int nt = 0; nt < 8; nt++) {
            s16x8 b = *(const s16x8*)&Ws[(nt * 16 + n16) * 136 + ks * 32 + quad * 8];
            acc[nt] = __builtin_amdgcn_mfma_f32_16x16x32_bf16(a, b, acc[nt], 0, 0, 0);
        }
    }

    const int bt    = m0 >> 10;
    const int nbase = (m0 & 1023) + wave * 16 + quad * 4;
    if (z == 2) {
        // V transposed [bt][h][hd][n]: lane holds 4 consecutive n for hd=n16
        #pragma unroll
        for (int nt = 0; nt < 8; nt++) {
            float bb = bias[nt * 16 + n16];
            u32x2 pv = {pack_bf16(acc[nt][0] + bb, acc[nt][1] + bb),
                        pack_bf16(acc[nt][2] + bb, acc[nt][3] + bb)};
            *(u32x2*)&out[((size_t)(bt * 8 + nt) * 16 + n16) * 1024 + nbase] = pv;
        }
    } else {
        // q/k [bt][h][n][hd]: transpose through Xs (done with it) -> coalesced stores
        __syncthreads();
        const int crow = wave * 16 + quad * 4;
        #pragma unroll
        for (int nt = 0; nt < 8; nt++) {
            float bb = bias[nt * 16 + n16];
            #pragma unroll
            for (int r = 0; r < 4; r++)
                Xs[(crow + r) * 136 + nt * 16 + n16] = f2bf((acc[nt][r] + bb) * scale);
        }
        __syncthreads();
        #pragma unroll
        for (int p = 0; p < 4; p++) {
            int g = p * 256 + t, row = g >> 4, ch = g & 15;   // ch*8 = h*16 + seg
            s16x8 val = *(const s16x8*)&Xs[row * 136 + ch * 8];
            *(s16x8*)&out[((size_t)(bt * 8 + (ch >> 1)) * 1024 + (m0 & 1023) + row) * 16
                          + (ch & 1) * 8] = val;
        }
    }
}

// ---------------------------------------------------------------- attention ---
// grid (8, 8, 24): x = head (XCD swizzle: flat%8 == h), y = 128-row q block,
// z = bt.  4 waves x 32 q-rows each.  128-j chunks, double-buffered.
// LDS map: [0,8192) K dbuf (2x4KB, per-window 64 linear 16B blocks, pi in
// global src); [8192,16384) V dbuf (2x4KB, XOR-swizzled); [16384,16448) ones.
__global__ __launch_bounds__(256, 6)
void attn_kernel(const unsigned short* __restrict__ q,
                 const unsigned short* __restrict__ k,
                 const unsigned short* __restrict__ vt,
                 unsigned short* __restrict__ O)
{
    __shared__ unsigned char smem[16448];

    const int t    = threadIdx.x;
    const int lane = t & 63;
    const int wave = t >> 6;
    const int hi   = lane >> 5;          // lane half
    const int l31  = lane & 31;
    const int h = blockIdx.x, bx = blockIdx.y, bt = blockIdx.z;
    const size_t headoff = (size_t)(bt * 8 + h) * 16384;

    const int q0 = bx * 128 + wave * 32;

    // Q B-frag (loop-invariant): B[k=hd][n=q]; lane: n=q0+l31, hd=hi*8..+7
    s16x8 qf = *(const s16x8*)(q + headoff + (size_t)(q0 + l31) * 16 + hi * 8);

    // ones block (64 B, covers addr and addr^32) for denominator A-rows 16..31
    if (t < 16) *(unsigned*)&smem[16384 + t * 4] = 0x3F803F80u;

    // --- staging: global_load_lds, dest = linear slot (wave base + lane*16) ---
    // K: wave w stages window w; lane -> m = lane&31 (holds j = pi(m)), kss = lane>>5
    const int km_ = lane & 31;
    const int kpi = (km_ & ~12) | ((km_ & 4) << 1) | ((km_ & 8) >> 1);  // pi(m)
    const unsigned short* kg =
        k + headoff + (size_t)(wave * 32 + kpi) * 16 + (lane >> 5) * 8;
    // V: slot t -> m = t>>4, o = (t&15) ^ (m&7)  (swizzle folded into source)
    const int vm_ = t >> 4;
    const int vo_ = (t & 15) ^ (vm_ & 7);
    const unsigned short* vg = vt + headoff + (size_t)vm_ * 1024 + vo_ * 8;
    // LDS dests (buffer 0)
    const unsigned kdst = (unsigned)(wave * 1024 + lane * 16);
    const unsigned vdst = (unsigned)(8192 + wave * 1024 + lane * 16);

    // V read row term: data lanes -> swizzled block base; A-rows 16..31 -> ones
    const unsigned vrow = (l31 < 16) ? (unsigned)(l31 * 256) : 0xFFFFFFFFu;

    // --- prologue: stage chunk 0 into buffer 0 ---
    gload16(kg, (unsigned short*)&smem[kdst]);
    gload16(vg, (unsigned short*)&smem[vdst]);

    f32x16 acc;
    #pragma unroll
    for (int i = 0; i < 16; i++) acc[i] = 0.f;
    f32x16 zero16;
    #pragma unroll
    for (int i = 0; i < 16; i++) zero16[i] = 0.f;

    #pragma unroll
    for (int c = 0; c < 8; c++) {
        __syncthreads();                          // buf[c&1] staged; other free
        if (c < 7) {                              // prefetch next chunk
            unsigned nb = ((c + 1) & 1) ? 4096u : 0u;
            gload16(kg + (size_t)(c + 1) * 2048, (unsigned short*)&smem[kdst + nb]);
            gload16(vg + (size_t)(c + 1) * 128,  (unsigned short*)&smem[vdst + nb]);
        }
        const unsigned kb  = (unsigned)((c & 1) * 4096) + (unsigned)(lane * 16);
        const unsigned vb0 = 8192u + (unsigned)((c & 1) * 4096);
        #pragma unroll
        for (int w = 0; w < 4; w++) {             // 4 windows of 32 j
            // S^T = K*Q for 32j x 32q in ONE mfma: C[m][q], j = pi(m) folded in
            s16x8 ka = *(const s16x8*)&smem[kb + w * 1024];
            f32x16 s = mfma3216(ka, qf, zero16);
            u32x4 pa0, pa1;
            #pragma unroll
            for (int i = 0; i < 4; i++) {
                pa0[i] = pack_bf16(__builtin_amdgcn_exp2f(s[2 * i]),
                                   __builtin_amdgcn_exp2f(s[2 * i + 1]));
                pa1[i] = pack_bf16(__builtin_amdgcn_exp2f(s[8 + 2 * i]),
                                   __builtin_amdgcn_exp2f(s[8 + 2 * i + 1]));
            }
            // V A-frag: data lanes read swizzled slot; lanes 16..31 read ones
            unsigned vaddr = (vrow == 0xFFFFFFFFu)
                ? 16384u
                : vb0 + vrow + (unsigned)(((((w << 2) + hi) ^ (l31 & 7))) << 4);
            s16x8 vf0 = *(const s16x8*)&smem[vaddr];
            s16x8 vf1 = *(const s16x8*)&smem[vaddr ^ 32u];
            acc = mfma3216(vf0, __builtin_bit_cast(s16x8, pa0), acc);
            acc = mfma3216(vf1, __builtin_bit_cast(s16x8, pa1), acc);
        }
    }

    // --- epilogue: acc[8] = denominator (C row 16 lo / 20 hi, ones A-rows) ---
    float dinv = __builtin_amdgcn_rcpf(acc[8]);
    __syncthreads();                              // all K/V reads retired
    // Otile [128 q][20 shorts pad] reusing K region; lane owns q-col = l31,
    // hd rows: lo {0-3,8-11}, hi {4-7,12-15}
    const unsigned ob = (unsigned)((wave * 32 + l31) * 40);
    u32x2 w0 = { pack_bf16(acc[0] * dinv, acc[1] * dinv),
                 pack_bf16(acc[2] * dinv, acc[3] * dinv) };
    u32x2 w1 = { pack_bf16(acc[4] * dinv, acc[5] * dinv),
                 pack_bf16(acc[6] * dinv, acc[7] * dinv) };
    *(u32x2*)&smem[ob + hi * 8]      = w0;        // hd 0-3 / 4-7
    *(u32x2*)&smem[ob + 16 + hi * 8] = w1;        // hd 8-11 / 12-15
    __syncthreads();
    {
        int qq = t >> 1, half = t & 1;
        s16x8 ov = *(const s16x8*)&smem[qq * 40 + half * 16];
        *(s16x8*)&O[((size_t)bt * 1024 + bx * 128 + qq) * 128 + h * 16 + half * 8] = ov;
    }
}

// ---------------------------------------------------------------- out proj ---
// X is bf16 (attn output) -> straight b128 staging; W fp32 -> bf16 in LDS.
__global__ __launch_bounds__(256)
void o_proj_kernel(const unsigned short* __restrict__ X, const float* __restrict__ W,
                   const float* __restrict__ bias, float* __restrict__ out)
{
    __shared__ unsigned short Xs[64 * 136];
    __shared__ unsigned short Ws[128 * 136];

    const int t  = threadIdx.x;
    const int m0 = blockIdx.x * 64;

    {
        #pragma unroll
        for (int p = 0; p < 4; p++) {          // 64x128 bf16: 1024 b128 chunks
            int g = p * 256 + t, row = g >> 4, ch = g & 15;
            *(s16x8*)&Xs[row * 136 + ch * 8] =
                *(const s16x8*)(X + (size_t)(m0 + row) * 128 + ch * 8);
        }
        const float4* Wg = (const float4*)W;
        #pragma unroll
        for (int p = 0; p < 16; p++) {
            int g = p * 256 + t;
            float4 vv = Wg[g];
            int row = g >> 5, c4 = g & 31;
            ushort4 d;
            d.x = f2bf(vv.x); d.y = f2bf(vv.y); d.z = f2bf(vv.z); d.w = f2bf(vv.w);
            *(ushort4*)&Ws[row * 136 + c4 * 4] = d;
        }
    }
    __syncthreads();

    const int wave = t >> 6, lane = t & 63, quad = lane >> 4, n16 = lane & 15;
    f32x4 acc[8];
    const f32x4 zero4 = {0.f, 0.f, 0.f, 0.f};
    #pragma unroll
    for (int i = 0; i < 8; i++) acc[i] = zero4;

    #pragma unroll
    for (int ks = 0; ks < 4; ks++) {
        s16x8 a = *(const s16x8*)&Xs[(wave * 16 + n16) * 136 + ks * 32 + quad * 8];
        #pragma unroll
        for (int nt = 0; nt < 8; nt++) {
            s16x8 b = *(const s16x8*)&Ws[(nt * 16 + n16) * 136 + ks * 32 + quad * 8];
            acc[nt] = __builtin_amdgcn_mfma_f32_16x16x32_bf16(a, b, acc[nt], 0, 0, 0);
        }
    }

    const int mrow = m0 + wave * 16 + quad * 4;
    #pragma unroll
    for (int nt = 0; nt < 8; nt++) {
        float bb = bias[nt * 16 + n16];
        #pragma unroll
        for (int r = 0; r < 4; r++)
            out[(size_t)(mrow + r) * 128 + nt * 16 + n16] = acc[nt][r] + bb;
    }
}

// ------------------------------------------------------------------ launch ---
extern "C" void kernel_launch(void* const* d_in, const int* in_sizes, int n_in,
                              void* d_out, int out_size, void* d_ws, size_t ws_size,
                              hipStream_t stream)
{
    const float* query = (const float*)d_in[0];
    const float* key_  = (const float*)d_in[1];
    const float* value = (const float*)d_in[2];
    const float* Wq = (const float*)d_in[3];
    const float* bq = (const float*)d_in[4];
    const float* Wk = (const float*)d_in[5];
    const float* bk = (const float*)d_in[6];
    const float* Wv = (const float*)d_in[7];
    const float* bv = (const float*)d_in[8];
    const float* Wo = (const float*)d_in[9];
    const float* bo = (const float*)d_in[10];
    float* out = (float*)d_out;

    char* ws = (char*)d_ws;
    unsigned short* qb = (unsigned short*)(ws);             // [bt][h][n][hd] bf16
    unsigned short* kb = (unsigned short*)(ws + 6291456);   // [bt][h][n][hd] bf16
    unsigned short* vb = (unsigned short*)(ws + 12582912);  // [bt][h][hd][n] bf16
    unsigned short* Ob = (unsigned short*)(ws + 18874368);  // [bt*1024][128] bf16

    qkv_proj_kernel<<<dim3(384, 3, 1), 256, 0, stream>>>(
        query, key_, value, Wq, Wk, Wv, bq, bk, bv, qb, kb, vb);
    attn_kernel<<<dim3(8, 8, 24), 256, 0, stream>>>(qb, kb, vb, Ob);
    o_proj_kernel<<<dim3(384, 1, 1), 256, 0, stream>>>(Ob, Wo, bo, out);
}